// Round 9
// baseline (256.129 us; speedup 1.0000x reference)
//
#include <hip/hip_runtime.h>
#include <hip/hip_bf16.h>
#include <stdint.h>
#include <stddef.h>

using short8  = __attribute__((ext_vector_type(8))) short;
using short4v = __attribute__((ext_vector_type(4))) short;
using int4v   = __attribute__((ext_vector_type(4))) int;
using f32x4   = __attribute__((ext_vector_type(4))) float;
typedef __hip_bfloat16 bf16_t;

__device__ __forceinline__ void glds16(const void* g, const void* l) {
  __builtin_amdgcn_global_load_lds(
      (const __attribute__((address_space(1))) void*)g,
      (__attribute__((address_space(3))) void*)l, 16, 0, 0);
}
__device__ __forceinline__ short bfbits(float x) {
  bf16_t h = __float2bfloat16(x);
  return __builtin_bit_cast(short, h);
}
// pack two fp32 -> two bf16 (RTZ) in one v_perm_b32
__device__ __forceinline__ int pk2(float lo, float hi) {
  return __builtin_amdgcn_perm(__builtin_bit_cast(unsigned, hi),
                               __builtin_bit_cast(unsigned, lo), 0x07060302u);
}

// ---------------------------------------------------------------------------
// Fused preprocessing (unchanged, proven r3-r8). Self-probing dtype flag.
// ---------------------------------------------------------------------------
__global__ __launch_bounds__(256)
void preprocess(const void* __restrict__ Wqkv, bf16_t* __restrict__ WqkvT,
                const void* __restrict__ Wout, bf16_t* __restrict__ WoutT,
                const void* __restrict__ Xv, bf16_t* __restrict__ Xb,
                int* __restrict__ flag) {
  __shared__ int sbad;
  __shared__ float tile[32][33];
  const int tid = threadIdx.x;
  const int bid = blockIdx.x;
  if (tid == 0) sbad = 0;
  __syncthreads();
  {
    int bad = 0;
    const unsigned short* wp = (const unsigned short*)Wqkv;
#pragma unroll
    for (int j = 0; j < 4; ++j) {
      float f = __uint_as_float((unsigned)wp[tid + j * 256] << 16);
      if (!(fabsf(f) <= 1e10f)) bad = 1;
    }
    if (bad) sbad = 1;  // benign race: same value
  }
  __syncthreads();
  const int isf = sbad;
  if (bid == 0 && tid == 0) *flag = isf;

  if (bid < 4096) {
    int bx = bid & 127;
    const int by = bid >> 7;
    const int tx = tid & 31, ty = tid >> 5;
    const void* Wv;
    bf16_t* Wt;
    int C;
    if (bx < 96) {
      Wv = Wqkv; Wt = WqkvT; C = 3072;
    } else {
      bx -= 96; Wv = Wout; Wt = WoutT; C = 1024;
    }
    const int n0 = bx * 32, k0 = by * 32;
#pragma unroll
    for (int j = 0; j < 4; ++j) {
      const int k = k0 + ty + j * 8;
      tile[ty + j * 8][tx] =
          isf ? ((const float*)Wv)[(size_t)k * C + n0 + tx]
              : __bfloat162float(((const bf16_t*)Wv)[(size_t)k * C + n0 + tx]);
    }
    __syncthreads();
#pragma unroll
    for (int j = 0; j < 4; ++j) {
      const int n = n0 + ty + j * 8;
      Wt[(size_t)n * 1024 + k0 + tx] = __float2bfloat16(tile[tx][ty + j * 8]);
    }
  } else {
    const int i = ((bid - 4096) * 256 + tid) * 4;
    if (isf) {
      const float4 v = *(const float4*)((const float*)Xv + i);
      Xb[i + 0] = __float2bfloat16(v.x);
      Xb[i + 1] = __float2bfloat16(v.y);
      Xb[i + 2] = __float2bfloat16(v.z);
      Xb[i + 3] = __float2bfloat16(v.w);
    } else {
      *(uint2*)(Xb + i) = *(const uint2*)((const bf16_t*)Xv + i);
    }
  }
}

// ---------------------------------------------------------------------------
// C[M,N] = A[M,K] * Bt[N,K]^T + bias.  256x128 tile, 512 thr (8 waves 4Mx2N).
// r9: T3+T4 counted-vmcnt pipeline. r5-r8 showed every drain-to-0 schedule
// (single-buf, 2-phase dbuf) pins MfmaUtil at 27-30%; catalog says the gain
// IS the counted vmcnt (m218). 3-deep ring: 3 tiles x {A0,A1,B} x 16KB =
// 144KB LDS (1 block/CU); tile t+2 staged during tile t; s_waitcnt vmcnt(6)
// at tile end (next tile's 6 loads stay in flight - NEVER 0 until epilogue);
// raw s_barrier once per tile; 2 phases x 16 MFMA with setprio. Grids exact:
// 768 = 3 CU-rounds, 256 = 1. Fragments/epilogue identical to r8 (proven).
// MODE 0: store C.  MODE 1: scatter to Q (pre-scaled by CSC), K, V^T bf16.
// ---------------------------------------------------------------------------
template <int MODE>
__global__ __launch_bounds__(512)
void gemm_k(const bf16_t* __restrict__ A, const bf16_t* __restrict__ Bt,
            const void* __restrict__ biasv, void* __restrict__ Cv,
            bf16_t* __restrict__ Qo, bf16_t* __restrict__ Ko,
            bf16_t* __restrict__ Vo, int M, int N, int K,
            const int* __restrict__ flag) {
  constexpr float CSC = 0.18033688011112042f;  // (1/sqrt(64)) * log2(e)
  // ring: slot layout per tile buf: [A0 16KB][A1 16KB][B 16KB] = 48KB x 3
  __shared__ __align__(16) bf16_t lds[9 * 8192];  // 144 KB

  const int isf32 = *flag;
  const int tid  = threadIdx.x;
  const int w    = tid >> 6;
  const int lane = tid & 63;
  const int lrow = lane & 15;
  const int quad = lane >> 4;
  const int m0 = blockIdx.x * 256;
  const int n0 = blockIdx.y * 128;
  const int wm = (w >> 1) * 64;   // 0..192
  const int wn = (w & 1) * 64;    // 0..64
  const int NT = K >> 6;

  f32x4 acc[4][4];
  for (int i = 0; i < 4; ++i)
    for (int j = 0; j < 4; ++j)
      for (int r = 0; r < 4; ++r) acc[i][j][r] = 0.f;

  // hoisted per-lane staging offsets (bytes); per K-tile just += kt*2
  const char* Ab = (const char*)A;
  const char* Bb = (const char*)Bt;
  unsigned a0off[2], a1off[2], boff[2];
  int lof[2];
#pragma unroll
  for (int i = 0; i < 2; ++i) {  // 1024 16B-chunks per 128-row half / 512 thr
    const int c = i * 512 + tid;
    const int row = c >> 3;                    // 0..127 within half
    const int q = (c & 7) ^ (row & 7);         // XOR source swizzle
    a0off[i] = (unsigned)((m0 + row) * K + q * 8) * 2u;
    a1off[i] = (unsigned)((m0 + 128 + row) * K + q * 8) * 2u;
    boff[i]  = (unsigned)((n0 + row) * K + q * 8) * 2u;
    lof[i] = c * 16;
  }
  char* ldsc = (char*)lds;

  auto stageA = [&](int buf, int kt) {  // 4 glds16/thread
    const unsigned kb = (unsigned)kt * 2u;
    char* base = ldsc + buf * 49152;
#pragma unroll
    for (int i = 0; i < 2; ++i) {
      glds16(Ab + a0off[i] + kb, base + lof[i]);
      glds16(Ab + a1off[i] + kb, base + 16384 + lof[i]);
    }
  };
  auto stageB = [&](int buf, int kt) {  // 2 glds16/thread
    const unsigned kb = (unsigned)kt * 2u;
    char* base = ldsc + buf * 49152 + 32768;
#pragma unroll
    for (int i = 0; i < 2; ++i) glds16(Bb + boff[i] + kb, base + lof[i]);
  };

  // frag read constants: rows within half have (row&7) == (lrow&7)
  const int sl0 = ((0 + quad) ^ (lrow & 7)) * 16;  // ks=0 slot byte offset
  const int sl1 = ((4 + quad) ^ (lrow & 7)) * 16;  // ks=1
  const int aseg = (wm >= 128) ? 16384 : 0;        // A0 or A1 sub-buffer
  const int arb  = (wm & 64) + lrow;               // row base within half
  const int brb  = wn + lrow;

  // prologue: tiles 0 and 1 fully staged; wait tile 0 (6 oldest), keep 6 fly
  stageA(0, 0); stageB(0, 0);
  stageA(1, 64); stageB(1, 64);
  asm volatile("s_waitcnt vmcnt(6)" ::: "memory");
  __builtin_amdgcn_s_barrier();

  int cur = 0;
  for (int t = 0; t < NT; ++t) {
    const char* base = ldsc + cur * 49152;
    int tgt = cur + 2; if (tgt >= 3) tgt -= 3;
    const bool more = (t + 2) < NT;

    // -- P1: ks=0 frags ; stage t+2 A-halves ; 16 MFMA
    short8 af0[4], bf0[4];
#pragma unroll
    for (int mi = 0; mi < 4; ++mi)
      af0[mi] = *(const short8*)(base + aseg + (arb + mi * 16) * 128 + sl0);
#pragma unroll
    for (int ni = 0; ni < 4; ++ni)
      bf0[ni] = *(const short8*)(base + 32768 + (brb + ni * 16) * 128 + sl0);
    if (more) stageA(tgt, (t + 2) * 64);
    __builtin_amdgcn_s_setprio(1);
#pragma unroll
    for (int mi = 0; mi < 4; ++mi)
#pragma unroll
      for (int ni = 0; ni < 4; ++ni)
        acc[mi][ni] = __builtin_amdgcn_mfma_f32_16x16x32_bf16(
            af0[mi], bf0[ni], acc[mi][ni], 0, 0, 0);
    __builtin_amdgcn_s_setprio(0);

    // -- P2: ks=1 frags ; stage t+2 B ; 16 MFMA
    short8 af1[4], bf1[4];
#pragma unroll
    for (int mi = 0; mi < 4; ++mi)
      af1[mi] = *(const short8*)(base + aseg + (arb + mi * 16) * 128 + sl1);
#pragma unroll
    for (int ni = 0; ni < 4; ++ni)
      bf1[ni] = *(const short8*)(base + 32768 + (brb + ni * 16) * 128 + sl1);
    if (more) stageB(tgt, (t + 2) * 64);
    __builtin_amdgcn_s_setprio(1);
#pragma unroll
    for (int mi = 0; mi < 4; ++mi)
#pragma unroll
      for (int ni = 0; ni < 4; ++ni)
        acc[mi][ni] = __builtin_amdgcn_mfma_f32_16x16x32_bf16(
            af1[mi], bf1[ni], acc[mi][ni], 0, 0, 0);
    __builtin_amdgcn_s_setprio(0);

    // tile end: wait next tile's 6 loads complete; keep t+2's 6 in flight.
    if (more)
      asm volatile("s_waitcnt vmcnt(6)" ::: "memory");
    else
      asm volatile("s_waitcnt vmcnt(0)" ::: "memory");
    __builtin_amdgcn_s_barrier();
    cur = (cur + 1 == 3) ? 0 : cur + 1;
  }

  // epilogue: C/D layout col=lane&15, row=quad*4+reg (identical to r8)
  if (MODE == 1) {
    const int sec = n0 >> 10;          // block-uniform (BN=128, 1024-aligned)
    const int b = m0 >> 11;            // block-uniform
    const int s0 = (m0 & 2047) + wm + quad * 4;
#pragma unroll
    for (int mi = 0; mi < 4; ++mi) {
#pragma unroll
      for (int ni = 0; ni < 4; ++ni) {
        const int col = n0 + wn + ni * 16 + lrow;
        const float bv = isf32 ? ((const float*)biasv)[col]
                               : __bfloat162float(((const bf16_t*)biasv)[col]);
        const int h = (col >> 6) & 15, d = col & 63;
        const int s = s0 + mi * 16;
        if (sec == 2) {  // V^T[bh][d][s]: 4 consecutive s -> one 8B store
          short4v hv4;
#pragma unroll
          for (int r = 0; r < 4; ++r) hv4[r] = bfbits(acc[mi][ni][r] + bv);
          *(short4v*)(Vo + ((((size_t)b * 16 + h) * 64) + d) * 2048 + s) = hv4;
        } else if (sec == 0) {  // Q, pre-scaled by CSC
          bf16_t* dst = Qo + ((((size_t)b * 16 + h) * 2048) + s) * 64 + d;
#pragma unroll
          for (int r = 0; r < 4; ++r)
            dst[(size_t)r * 64] = __float2bfloat16((acc[mi][ni][r] + bv) * CSC);
        } else {
          bf16_t* dst = Ko + ((((size_t)b * 16 + h) * 2048) + s) * 64 + d;
#pragma unroll
          for (int r = 0; r < 4; ++r)
            dst[(size_t)r * 64] = __float2bfloat16(acc[mi][ni][r] + bv);
        }
      }
    }
  } else {
#pragma unroll
    for (int mi = 0; mi < 4; ++mi) {
#pragma unroll
      for (int ni = 0; ni < 4; ++ni) {
        const int col = n0 + wn + ni * 16 + lrow;
        const float bv = isf32 ? ((const float*)biasv)[col]
                               : __bfloat162float(((const bf16_t*)biasv)[col]);
#pragma unroll
        for (int r = 0; r < 4; ++r) {
          const int row = m0 + wm + mi * 16 + quad * 4 + r;
          const float val = acc[mi][ni][r] + bv;
          if (isf32)
            ((float*)Cv)[(size_t)row * N + col] = val;
          else
            ((bf16_t*)Cv)[(size_t)row * N + col] = __float2bfloat16(val);
        }
      }
    }
  }
}

// ---------------------------------------------------------------------------
// Flash attention: unchanged from r8 (proven 73us): transposed-score +
// x32-PV + glds16 double-buffer, qt=4, QK-hoist pipeline, zero-C first MFMA,
// setprio clusters. Structurally capped at 8 waves/CU (64 q-rows/wave).
// ---------------------------------------------------------------------------
__global__ __launch_bounds__(256, 2)
void attn_fwd(const bf16_t* __restrict__ Q, const bf16_t* __restrict__ K,
              const bf16_t* __restrict__ Vt, bf16_t* __restrict__ AO) {
  __shared__ __align__(16) bf16_t lK[2][64 * 64];  // [key][d], fk(row) swizzle
  __shared__ __align__(16) bf16_t lV[2][64 * 64];  // [d][key], row&7 swizzle

  const int tid  = threadIdx.x;
  const int w    = tid >> 6;
  const int lane = tid & 63;
  const int lrow = lane & 15;
  const int quad = lane >> 4;
  const int id = blockIdx.x;
  const int swz = (id & 7) * 64 + (id >> 3);  // XCD-contiguous bh chunks
  const int bh  = swz >> 3;
  const int q0  = (swz & 7) * 256;

  const bf16_t* Qb = Q + (size_t)bh * 2048 * 64;
  const bf16_t* Kb = K + (size_t)bh * 2048 * 64;
  const bf16_t* Vb = Vt + (size_t)bh * 64 * 2048;

  // per-lane constants for permuted K-frag reads
  const int rbase = (lrow >> 2) * 8 + (lrow & 3);
  const int fkl   = 2 * (lrow >> 2) + (lrow & 1);

  // Q fragments (B-operand): lane holds Q[q=lrow][d=ks*32+quad*8+j]
  short8 aq[4][2];
#pragma unroll
  for (int qt = 0; qt < 4; ++qt)
#pragma unroll
    for (int ks = 0; ks < 2; ++ks)
      aq[qt][ks] = *(const short8*)(Qb +
          (size_t)(q0 + w * 64 + qt * 16 + lrow) * 64 + ks * 32 + quad * 8);

  short8 ones;
#pragma unroll
  for (int j = 0; j < 8; ++j) ones[j] = (short)0x3F80;  // bf16 1.0

  const f32x4 zf = {0.f, 0.f, 0.f, 0.f};  // shared zero C-operand

  f32x4 ot[4][4];   // O^T[d-tile][q-tile]: d=quad*4+r, q=lrow
  f32x4 lsacc[4];   // sum-of-p per q (replicated over quads)
#pragma unroll
  for (int dt = 0; dt < 4; ++dt)
#pragma unroll
    for (int qt = 0; qt < 4; ++qt)
#pragma unroll
      for (int r = 0; r < 4; ++r) ot[dt][qt][r] = 0.f;
#pragma unroll
  for (int qt = 0; qt < 4; ++qt)
#pragma unroll
    for (int r = 0; r < 4; ++r) lsacc[qt][r] = 0.f;

  // async staging: global source carries the XOR swizzle; LDS is lane-linear
  auto stage = [&](int buf, int kt) {
#pragma unroll
    for (int i = 0; i < 2; ++i) {
      const int cbase = i * 256 + w * 64;
      const int c = cbase + lane;
      const int row = c >> 3, ch = c & 7;
      const int fk = 2 * ((row >> 3) & 3) + (row & 1);
      glds16(Kb + (size_t)(kt + row) * 64 + (ch ^ fk) * 8,
             (const char*)lK[buf] + cbase * 16);
      glds16(Vb + (size_t)row * 2048 + kt + (ch ^ (row & 7)) * 8,
             (const char*)lV[buf] + cbase * 16);
    }
  };

  auto compute = [&](const bf16_t* lKb, const bf16_t* lVb) {
    f32x4 sc[2][2][4];  // [g][T][qt], both halves live across QK cluster
#pragma unroll
    for (int g = 0; g < 2; ++g) {
      short8 ak0[2], ak1[2];
#pragma unroll
      for (int T = 0; T < 2; ++T) {
        const int row = g * 32 + T * 4 + rbase;
        ak0[T] = *(const short8*)((const char*)lKb + row * 128 +
                                  ((0 * 4 + quad) ^ fkl) * 16);
        ak1[T] = *(const short8*)((const char*)lKb + row * 128 +
                                  ((1 * 4 + quad) ^ fkl) * 16);
      }
      __builtin_amdgcn_s_setprio(1);
#pragma unroll
      for (int T = 0; T < 2; ++T)
#pragma unroll
        for (int qt = 0; qt < 4; ++qt)
          sc[g][T][qt] = __builtin_amdgcn_mfma_f32_16x16x32_bf16(
              ak0[T], aq[qt][0], zf, 0, 0, 0);  // zero-C: no sc pre-init
#pragma unroll
      for (int T = 0; T < 2; ++T)
#pragma unroll
        for (int qt = 0; qt < 4; ++qt)
          sc[g][T][qt] = __builtin_amdgcn_mfma_f32_16x16x32_bf16(
              ak1[T], aq[qt][1], sc[g][T][qt], 0, 0, 0);
      __builtin_amdgcn_s_setprio(0);
    }
    // per-half: softmax (trans pipe) then lsacc+PV (matrix pipe); the g=1
    // exp2 run issues while g=0's PV is still draining the matrix pipe.
#pragma unroll
    for (int g = 0; g < 2; ++g) {
      short8 pb[4];
#pragma unroll
      for (int qt = 0; qt < 4; ++qt) {
        float p[8];
#pragma unroll
        for (int T = 0; T < 2; ++T)
#pragma unroll
          for (int r = 0; r < 4; ++r)
            p[T * 4 + r] = __builtin_amdgcn_exp2f(sc[g][T][qt][r]);
        int4v pi = {pk2(p[0], p[1]), pk2(p[2], p[3]), pk2(p[4], p[5]),
                    pk2(p[6], p[7])};
        pb[qt] = __builtin_bit_cast(short8, pi);
      }

      __builtin_amdgcn_s_setprio(1);
#pragma unroll
      for (int qt = 0; qt < 4; ++qt)
        lsacc[qt] = __builtin_amdgcn_mfma_f32_16x16x32_bf16(ones, pb[qt],
                                                            lsacc[qt], 0, 0, 0);
#pragma unroll
      for (int dt = 0; dt < 4; ++dt) {
        const int row = dt * 16 + lrow;
        const int slot = (g * 4 + quad) ^ (row & 7);
        const short8 vf =
            *(const short8*)((const char*)lVb + row * 128 + slot * 16);
#pragma unroll
        for (int qt = 0; qt < 4; ++qt)
          ot[dt][qt] = __builtin_amdgcn_mfma_f32_16x16x32_bf16(
              vf, pb[qt], ot[dt][qt], 0, 0, 0);
      }
      __builtin_amdgcn_s_setprio(0);
    }
  };

  stage(0, 0);
  __syncthreads();  // drains vmcnt: buf0 ready

  for (int kt = 0; kt < 2048; kt += 128) {
    if (kt + 64 < 2048) stage(1, kt + 64);   // in flight during compute
    compute(lK[0], lV[0]);
    __syncthreads();                          // buf1 ready; buf0 readers done
    if (kt + 128 < 2048) stage(0, kt + 128);
    compute(lK[1], lV[1]);
    __syncthreads();
  }

  // scale + store O^T -> AO[b*2048+s][h*64+d]
  const int b = bh >> 4, h = bh & 15;
#pragma unroll
  for (int qt = 0; qt < 4; ++qt) {
    const float inv = 1.f / lsacc[qt][0];
    const int srow = q0 + w * 64 + qt * 16 + lrow;
#pragma unroll
    for (int dt = 0; dt < 4; ++dt) {
      uint2 pack;
      short* ps = (short*)&pack;
#pragma unroll
      for (int r = 0; r < 4; ++r) ps[r] = bfbits(ot[dt][qt][r] * inv);
      *(uint2*)(AO + ((size_t)b * 2048 + srow) * 1024 + h * 64 + dt * 16 +
                quad * 4) = pack;
    }
  }
}

// ---------------------------------------------------------------------------
extern "C" void kernel_launch(void* const* d_in, const int* in_sizes, int n_in,
                              void* d_out, int out_size, void* d_ws,
                              size_t ws_size, hipStream_t stream) {
  const void* X    = d_in[0];
  const void* Wqkv = d_in[1];
  const void* bqkv = d_in[2];
  const void* Wout = d_in[3];
  const void* bout = d_in[4];

  char* ws = (char*)d_ws;
  bf16_t* WqkvT = (bf16_t*)(ws);               // [3072,1024]  6 MB
  bf16_t* WoutT = (bf16_t*)(ws + 6291456);     // [1024,1024]  2 MB
  bf16_t* Qw    = (bf16_t*)(ws + 8388608);     // [64,2048,64] 16 MB
  bf16_t* Kw    = (bf16_t*)(ws + 25165824);    // [64,2048,64] 16 MB
  bf16_t* Vw    = (bf16_t*)(ws + 41943040);    // [64,64,2048] 16 MB (V^T)
  bf16_t* AOw   = (bf16_t*)(ws + 58720256);    // [8192,1024]  16 MB
  bf16_t* Xbf   = AOw;  // aliases AOw: Xbf dead before attn writes AOw
  int*    flag  = (int*)(ws + 75497472);

  preprocess<<<12288, 256, 0, stream>>>(Wqkv, WqkvT, Wout, WoutT, X, Xbf, flag);

  gemm_k<1><<<dim3(32, 24), 512, 0, stream>>>(Xbf, WqkvT, bqkv, nullptr, Qw,
                                              Kw, Vw, 8192, 3072, 1024, flag);
  attn_fwd<<<512, 256, 0, stream>>>(Qw, Kw, Vw, AOw);
  gemm_k<0><<<dim3(32, 8), 512, 0, stream>>>(AOw, WoutT, bout, d_out, nullptr,
                                             nullptr, nullptr, 8192, 1024, 1024,
                                             flag);
}

// Round 10
// 247.905 us; speedup vs baseline: 1.0332x; 1.0332x over previous
//
#include <hip/hip_runtime.h>
#include <hip/hip_bf16.h>
#include <stdint.h>
#include <stddef.h>

using short8  = __attribute__((ext_vector_type(8))) short;
using short4v = __attribute__((ext_vector_type(4))) short;
using ushort4v= __attribute__((ext_vector_type(4))) unsigned short;
using int4v   = __attribute__((ext_vector_type(4))) int;
using f32x4   = __attribute__((ext_vector_type(4))) float;
typedef __hip_bfloat16 bf16_t;

__device__ __forceinline__ void glds16(const void* g, const void* l) {
  __builtin_amdgcn_global_load_lds(
      (const __attribute__((address_space(1))) void*)g,
      (__attribute__((address_space(3))) void*)l, 16, 0, 0);
}
__device__ __forceinline__ short bfbits(float x) {
  bf16_t h = __float2bfloat16(x);
  return __builtin_bit_cast(short, h);
}
__device__ __forceinline__ unsigned short bfbitsu(float x) {
  bf16_t h = __float2bfloat16(x);
  return __builtin_bit_cast(unsigned short, h);
}
// pack two fp32 -> two bf16 (RTZ) in one v_perm_b32
__device__ __forceinline__ int pk2(float lo, float hi) {
  return __builtin_amdgcn_perm(__builtin_bit_cast(unsigned, hi),
                               __builtin_bit_cast(unsigned, lo), 0x07060302u);
}

// ---------------------------------------------------------------------------
// Preprocess, BW-optimized (r10). r5-r9 dispatch accounting showed the old
// version costs 70-90us for ~75MB of traffic (~0.9 TB/s): scalar bf16
// stores, 64B transposed writes, 12288 tiny blocks. New: 64x64 transpose
// tiles (float4 reads, f32 LDS tile[64][65] = 2-way-free banks, ushort4
// 128B-contiguous writes) + X-convert at 8 elems/thread (2xfloat4 -> one
// 16B short8 store). Grid 5120. Self-probing dtype flag kept (block 0
// publishes for the GEMMs, stream-ordered).
// bid<768: Wqkv[1024,3072]->WqkvT. bid<1024: Wout->WoutT. else: X->bf16.
// ---------------------------------------------------------------------------
__global__ __launch_bounds__(256)
void preprocess(const void* __restrict__ Wqkv, bf16_t* __restrict__ WqkvT,
                const void* __restrict__ Wout, bf16_t* __restrict__ WoutT,
                const void* __restrict__ Xv, bf16_t* __restrict__ Xb,
                int* __restrict__ flag) {
  __shared__ int sbad;
  __shared__ float tile[64][65];
  const int tid = threadIdx.x;
  const int bid = blockIdx.x;
  if (tid == 0) sbad = 0;
  __syncthreads();
  {
    int bad = 0;
    const unsigned short* wp = (const unsigned short*)Wqkv;
#pragma unroll
    for (int j = 0; j < 4; ++j) {
      float f = __uint_as_float((unsigned)wp[tid + j * 256] << 16);
      if (!(fabsf(f) <= 1e10f)) bad = 1;
    }
    if (bad) sbad = 1;  // benign race: same value
  }
  __syncthreads();
  const int isf = sbad;
  if (bid == 0 && tid == 0) *flag = isf;

  if (bid < 1024) {
    // ---- weight transpose: 64x64 tile ----
    int bx = bid;
    const void* Wv;
    bf16_t* Wt;
    int C, NB;
    if (bx < 768) {
      Wv = Wqkv; Wt = WqkvT; C = 3072; NB = 48;  // 16 x 48 tiles
    } else {
      bx -= 768; Wv = Wout; Wt = WoutT; C = 1024; NB = 16;  // 16 x 16 tiles
    }
    const int k0 = (bx / NB) * 64;
    const int n0 = (bx % NB) * 64;
    const int tx = tid & 15, ty = tid >> 4;
#pragma unroll
    for (int p = 0; p < 4; ++p) {
      const int row = p * 16 + ty;
      if (isf) {
        const float4 v = *(const float4*)((const float*)Wv +
                                          (size_t)(k0 + row) * C + n0 + tx * 4);
        tile[row][tx * 4 + 0] = v.x;
        tile[row][tx * 4 + 1] = v.y;
        tile[row][tx * 4 + 2] = v.z;
        tile[row][tx * 4 + 3] = v.w;
      } else {
        const ushort4v v = *(const ushort4v*)((const unsigned short*)Wv +
                                              (size_t)(k0 + row) * C + n0 +
                                              tx * 4);
#pragma unroll
        for (int q = 0; q < 4; ++q)
          tile[row][tx * 4 + q] = __uint_as_float((unsigned)v[q] << 16);
      }
    }
    __syncthreads();
#pragma unroll
    for (int p = 0; p < 4; ++p) {
      const int n = p * 16 + ty;
      ushort4v o;
#pragma unroll
      for (int q = 0; q < 4; ++q) o[q] = bfbitsu(tile[tx * 4 + q][n]);
      *(ushort4v*)(Wt + (size_t)(n0 + n) * 1024 + k0 + tx * 4) = o;
    }
  } else {
    // ---- X -> bf16, 8 elems/thread ----
    const int i = ((bid - 1024) * 256 + tid) * 8;
    if (isf) {
      const float4 a = *(const float4*)((const float*)Xv + i);
      const float4 b = *(const float4*)((const float*)Xv + i + 4);
      short8 o;
      o[0] = bfbits(a.x); o[1] = bfbits(a.y);
      o[2] = bfbits(a.z); o[3] = bfbits(a.w);
      o[4] = bfbits(b.x); o[5] = bfbits(b.y);
      o[6] = bfbits(b.z); o[7] = bfbits(b.w);
      *(short8*)(Xb + i) = o;
    } else {
      *(uint4*)(Xb + i) = *(const uint4*)((const bf16_t*)Xv + i);
    }
  }
}

// ---------------------------------------------------------------------------
// C[M,N] = A[M,K] * Bt[N,K]^T + bias.  A,Bt bf16; bias/C dtype per flag.
// r8 kernel (proven best): 256x128 tile, 512 threads (8 waves = 4Mx2N of
// 64x64 wave-tiles), single-buffer 48KB LDS (2 blocks/CU -> cross-block
// overlap covers the drain; r9's counted-vmcnt @1 block/CU regressed).
// Grids exact: 32x24=768=3 rounds, 32x8=256=1 round. Hoisted staging addrs.
// MODE 0: store C.  MODE 1: scatter to Q (pre-scaled by CSC), K, V^T bf16.
// ---------------------------------------------------------------------------
template <int MODE>
__global__ __launch_bounds__(512)
void gemm_k(const bf16_t* __restrict__ A, const bf16_t* __restrict__ Bt,
            const void* __restrict__ biasv, void* __restrict__ Cv,
            bf16_t* __restrict__ Qo, bf16_t* __restrict__ Ko,
            bf16_t* __restrict__ Vo, int M, int N, int K,
            const int* __restrict__ flag) {
  constexpr float CSC = 0.18033688011112042f;  // (1/sqrt(64)) * log2(e)
  __shared__ __align__(16) bf16_t lA[256 * 64];  // 32 KB
  __shared__ __align__(16) bf16_t lB[128 * 64];  // 16 KB

  const int isf32 = *flag;
  const int tid  = threadIdx.x;
  const int w    = tid >> 6;
  const int lane = tid & 63;
  const int lrow = lane & 15;
  const int quad = lane >> 4;
  const int m0 = blockIdx.x * 256;
  const int n0 = blockIdx.y * 128;
  const int wm = (w >> 1) * 64;   // 0..192
  const int wn = (w & 1) * 64;    // 0..64

  f32x4 acc[4][4];
  for (int i = 0; i < 4; ++i)
    for (int j = 0; j < 4; ++j)
      for (int r = 0; r < 4; ++r) acc[i][j][r] = 0.f;

  // hoisted per-lane staging offsets (bytes); per K-step just += kt*2
  const char* Ab = (const char*)A;
  const char* Bb = (const char*)Bt;
  unsigned aoff[4], boff[2];
  int lda[4], ldb[2];
#pragma unroll
  for (int i = 0; i < 4; ++i) {  // A: 256 rows x 8 chunks = 2048 / 512 thr
    const int c = i * 512 + tid;
    const int row = c >> 3;
    const int q = (c & 7) ^ (row & 7);
    aoff[i] = (unsigned)((m0 + row) * K + q * 8) * 2u;
    lda[i] = c * 16;
  }
#pragma unroll
  for (int i = 0; i < 2; ++i) {  // B: 128 rows x 8 chunks = 1024 / 512 thr
    const int c = i * 512 + tid;
    const int row = c >> 3;
    const int q = (c & 7) ^ (row & 7);
    boff[i] = (unsigned)((n0 + row) * K + q * 8) * 2u;
    ldb[i] = c * 16;
  }

  auto stage = [&](int kt) {
    const unsigned kb = (unsigned)kt * 2u;
#pragma unroll
    for (int i = 0; i < 4; ++i)
      glds16(Ab + aoff[i] + kb, (const char*)lA + lda[i]);
#pragma unroll
    for (int i = 0; i < 2; ++i)
      glds16(Bb + boff[i] + kb, (const char*)lB + ldb[i]);
  };

  for (int kt = 0; kt < K; kt += 64) {
    stage(kt);
    __syncthreads();  // drains vmcnt: tile ready
#pragma unroll
    for (int ks = 0; ks < 2; ++ks) {
      short8 af[4], bfr[4];
#pragma unroll
      for (int mi = 0; mi < 4; ++mi) {
        const int row = wm + mi * 16 + lrow;
        const int slot = (ks * 4 + quad) ^ (row & 7);
        af[mi] = *(const short8*)((const char*)lA + row * 128 + slot * 16);
      }
#pragma unroll
      for (int ni = 0; ni < 4; ++ni) {
        const int row = wn + ni * 16 + lrow;
        const int slot = (ks * 4 + quad) ^ (row & 7);
        bfr[ni] = *(const short8*)((const char*)lB + row * 128 + slot * 16);
      }
#pragma unroll
      for (int mi = 0; mi < 4; ++mi)
#pragma unroll
        for (int ni = 0; ni < 4; ++ni)
          acc[mi][ni] = __builtin_amdgcn_mfma_f32_16x16x32_bf16(
              af[mi], bfr[ni], acc[mi][ni], 0, 0, 0);
    }
    __syncthreads();  // readers done before next stage overwrites (WAR)
  }

  // epilogue: C/D layout col=lane&15, row=quad*4+reg
  if (MODE == 1) {
    const int sec = n0 >> 10;          // block-uniform (BN=128, 1024-aligned)
    const int b = m0 >> 11;            // block-uniform
    const int s0 = (m0 & 2047) + wm + quad * 4;
#pragma unroll
    for (int mi = 0; mi < 4; ++mi) {
#pragma unroll
      for (int ni = 0; ni < 4; ++ni) {
        const int col = n0 + wn + ni * 16 + lrow;
        const float bv = isf32 ? ((const float*)biasv)[col]
                               : __bfloat162float(((const bf16_t*)biasv)[col]);
        const int h = (col >> 6) & 15, d = col & 63;
        const int s = s0 + mi * 16;
        if (sec == 2) {  // V^T[bh][d][s]: 4 consecutive s -> one 8B store
          short4v hv4;
#pragma unroll
          for (int r = 0; r < 4; ++r) hv4[r] = bfbits(acc[mi][ni][r] + bv);
          *(short4v*)(Vo + ((((size_t)b * 16 + h) * 64) + d) * 2048 + s) = hv4;
        } else if (sec == 0) {  // Q, pre-scaled by CSC
          bf16_t* dst = Qo + ((((size_t)b * 16 + h) * 2048) + s) * 64 + d;
#pragma unroll
          for (int r = 0; r < 4; ++r)
            dst[(size_t)r * 64] = __float2bfloat16((acc[mi][ni][r] + bv) * CSC);
        } else {
          bf16_t* dst = Ko + ((((size_t)b * 16 + h) * 2048) + s) * 64 + d;
#pragma unroll
          for (int r = 0; r < 4; ++r)
            dst[(size_t)r * 64] = __float2bfloat16(acc[mi][ni][r] + bv);
        }
      }
    }
  } else {
#pragma unroll
    for (int mi = 0; mi < 4; ++mi) {
#pragma unroll
      for (int ni = 0; ni < 4; ++ni) {
        const int col = n0 + wn + ni * 16 + lrow;
        const float bv = isf32 ? ((const float*)biasv)[col]
                               : __bfloat162float(((const bf16_t*)biasv)[col]);
#pragma unroll
        for (int r = 0; r < 4; ++r) {
          const int row = m0 + wm + mi * 16 + quad * 4 + r;
          const float val = acc[mi][ni][r] + bv;
          if (isf32)
            ((float*)Cv)[(size_t)row * N + col] = val;
          else
            ((bf16_t*)Cv)[(size_t)row * N + col] = __float2bfloat16(val);
        }
      }
    }
  }
}

// ---------------------------------------------------------------------------
// Flash attention: unchanged from r8 (proven 73us): transposed-score +
// x32-PV + glds16 double-buffer, qt=4, QK-hoist pipeline, zero-C first MFMA,
// setprio clusters. Structurally capped at 8 waves/CU (64 q-rows/wave).
// ---------------------------------------------------------------------------
__global__ __launch_bounds__(256, 2)
void attn_fwd(const bf16_t* __restrict__ Q, const bf16_t* __restrict__ K,
              const bf16_t* __restrict__ Vt, bf16_t* __restrict__ AO) {
  __shared__ __align__(16) bf16_t lK[2][64 * 64];  // [key][d], fk(row) swizzle
  __shared__ __align__(16) bf16_t lV[2][64 * 64];  // [d][key], row&7 swizzle

  const int tid  = threadIdx.x;
  const int w    = tid >> 6;
  const int lane = tid & 63;
  const int lrow = lane & 15;
  const int quad = lane >> 4;
  const int id = blockIdx.x;
  const int swz = (id & 7) * 64 + (id >> 3);  // XCD-contiguous bh chunks
  const int bh  = swz >> 3;
  const int q0  = (swz & 7) * 256;

  const bf16_t* Qb = Q + (size_t)bh * 2048 * 64;
  const bf16_t* Kb = K + (size_t)bh * 2048 * 64;
  const bf16_t* Vb = Vt + (size_t)bh * 64 * 2048;

  // per-lane constants for permuted K-frag reads
  const int rbase = (lrow >> 2) * 8 + (lrow & 3);
  const int fkl   = 2 * (lrow >> 2) + (lrow & 1);

  // Q fragments (B-operand): lane holds Q[q=lrow][d=ks*32+quad*8+j]
  short8 aq[4][2];
#pragma unroll
  for (int qt = 0; qt < 4; ++qt)
#pragma unroll
    for (int ks = 0; ks < 2; ++ks)
      aq[qt][ks] = *(const short8*)(Qb +
          (size_t)(q0 + w * 64 + qt * 16 + lrow) * 64 + ks * 32 + quad * 8);

  short8 ones;
#pragma unroll
  for (int j = 0; j < 8; ++j) ones[j] = (short)0x3F80;  // bf16 1.0

  const f32x4 zf = {0.f, 0.f, 0.f, 0.f};  // shared zero C-operand

  f32x4 ot[4][4];   // O^T[d-tile][q-tile]: d=quad*4+r, q=lrow
  f32x4 lsacc[4];   // sum-of-p per q (replicated over quads)
#pragma unroll
  for (int dt = 0; dt < 4; ++dt)
#pragma unroll
    for (int qt = 0; qt < 4; ++qt)
#pragma unroll
      for (int r = 0; r < 4; ++r) ot[dt][qt][r] = 0.f;
#pragma unroll
  for (int qt = 0; qt < 4; ++qt)
#pragma unroll
    for (int r = 0; r < 4; ++r) lsacc[qt][r] = 0.f;

  // async staging: global source carries the XOR swizzle; LDS is lane-linear
  auto stage = [&](int buf, int kt) {
#pragma unroll
    for (int i = 0; i < 2; ++i) {
      const int cbase = i * 256 + w * 64;
      const int c = cbase + lane;
      const int row = c >> 3, ch = c & 7;
      const int fk = 2 * ((row >> 3) & 3) + (row & 1);
      glds16(Kb + (size_t)(kt + row) * 64 + (ch ^ fk) * 8,
             (const char*)lK[buf] + cbase * 16);
      glds16(Vb + (size_t)row * 2048 + kt + (ch ^ (row & 7)) * 8,
             (const char*)lV[buf] + cbase * 16);
    }
  };

  auto compute = [&](const bf16_t* lKb, const bf16_t* lVb) {
    f32x4 sc[2][2][4];  // [g][T][qt], both halves live across QK cluster
#pragma unroll
    for (int g = 0; g < 2; ++g) {
      short8 ak0[2], ak1[2];
#pragma unroll
      for (int T = 0; T < 2; ++T) {
        const int row = g * 32 + T * 4 + rbase;
        ak0[T] = *(const short8*)((const char*)lKb + row * 128 +
                                  ((0 * 4 + quad) ^ fkl) * 16);
        ak1[T] = *(const short8*)((const char*)lKb + row * 128 +
                                  ((1 * 4 + quad) ^ fkl) * 16);
      }
      __builtin_amdgcn_s_setprio(1);
#pragma unroll
      for (int T = 0; T < 2; ++T)
#pragma unroll
        for (int qt = 0; qt < 4; ++qt)
          sc[g][T][qt] = __builtin_amdgcn_mfma_f32_16x16x32_bf16(
              ak0[T], aq[qt][0], zf, 0, 0, 0);  // zero-C: no sc pre-init
#pragma unroll
      for (int T = 0; T < 2; ++T)
#pragma unroll
        for (int qt = 0; qt < 4; ++qt)
          sc[g][T][qt] = __builtin_amdgcn_mfma_f32_16x16x32_bf16(
              ak1[T], aq[qt][1], sc[g][T][qt], 0, 0, 0);
      __builtin_amdgcn_s_setprio(0);
    }
    // per-half: softmax (trans pipe) then lsacc+PV (matrix pipe); the g=1
    // exp2 run issues while g=0's PV is still draining the matrix pipe.
#pragma unroll
    for (int g = 0; g < 2; ++g) {
      short8 pb[4];
#pragma unroll
      for (int qt = 0; qt < 4; ++qt) {
        float p[8];
#pragma unroll
        for (int T = 0; T < 2; ++T)
#pragma unroll
          for (int r = 0; r < 4; ++r)
            p[T * 4 + r] = __builtin_amdgcn_exp2f(sc[g][T][qt][r]);
        int4v pi = {pk2(p[0], p[1]), pk2(p[2], p[3]), pk2(p[4], p[5]),
                    pk2(p[6], p[7])};
        pb[qt] = __builtin_bit_cast(short8, pi);
      }

      __builtin_amdgcn_s_setprio(1);
#pragma unroll
      for (int qt = 0; qt < 4; ++qt)
        lsacc[qt] = __builtin_amdgcn_mfma_f32_16x16x32_bf16(ones, pb[qt],
                                                            lsacc[qt], 0, 0, 0);
#pragma unroll
      for (int dt = 0; dt < 4; ++dt) {
        const int row = dt * 16 + lrow;
        const int slot = (g * 4 + quad) ^ (row & 7);
        const short8 vf =
            *(const short8*)((const char*)lVb + row * 128 + slot * 16);
#pragma unroll
        for (int qt = 0; qt < 4; ++qt)
          ot[dt][qt] = __builtin_amdgcn_mfma_f32_16x16x32_bf16(
              vf, pb[qt], ot[dt][qt], 0, 0, 0);
      }
      __builtin_amdgcn_s_setprio(0);
    }
  };

  stage(0, 0);
  __syncthreads();  // drains vmcnt: buf0 ready

  for (int kt = 0; kt < 2048; kt += 128) {
    if (kt + 64 < 2048) stage(1, kt + 64);   // in flight during compute
    compute(lK[0], lV[0]);
    __syncthreads();                          // buf1 ready; buf0 readers done
    if (kt + 128 < 2048) stage(0, kt + 128);
    compute(lK[1], lV[1]);
    __syncthreads();
  }

  // scale + store O^T -> AO[b*2048+s][h*64+d]
  const int b = bh >> 4, h = bh & 15;
#pragma unroll
  for (int qt = 0; qt < 4; ++qt) {
    const float inv = 1.f / lsacc[qt][0];
    const int srow = q0 + w * 64 + qt * 16 + lrow;
#pragma unroll
    for (int dt = 0; dt < 4; ++dt) {
      uint2 pack;
      short* ps = (short*)&pack;
#pragma unroll
      for (int r = 0; r < 4; ++r) ps[r] = bfbits(ot[dt][qt][r] * inv);
      *(uint2*)(AO + ((size_t)b * 2048 + srow) * 1024 + h * 64 + dt * 16 +
                quad * 4) = pack;
    }
  }
}

// ---------------------------------------------------------------------------
extern "C" void kernel_launch(void* const* d_in, const int* in_sizes, int n_in,
                              void* d_out, int out_size, void* d_ws,
                              size_t ws_size, hipStream_t stream) {
  const void* X    = d_in[0];
  const void* Wqkv = d_in[1];
  const void* bqkv = d_in[2];
  const void* Wout = d_in[3];
  const void* bout = d_in[4];

  char* ws = (char*)d_ws;
  bf16_t* WqkvT = (bf16_t*)(ws);               // [3072,1024]  6 MB
  bf16_t* WoutT = (bf16_t*)(ws + 6291456);     // [1024,1024]  2 MB
  bf16_t* Qw    = (bf16_t*)(ws + 8388608);     // [64,2048,64] 16 MB
  bf16_t* Kw    = (bf16_t*)(ws + 25165824);    // [64,2048,64] 16 MB
  bf16_t* Vw    = (bf16_t*)(ws + 41943040);    // [64,64,2048] 16 MB (V^T)
  bf16_t* AOw   = (bf16_t*)(ws + 58720256);    // [8192,1024]  16 MB
  bf16_t* Xbf   = AOw;  // aliases AOw: Xbf dead before attn writes AOw
  int*    flag  = (int*)(ws + 75497472);

  preprocess<<<5120, 256, 0, stream>>>(Wqkv, WqkvT, Wout, WoutT, X, Xbf, flag);

  gemm_k<1><<<dim3(32, 24), 512, 0, stream>>>(Xbf, WqkvT, bqkv, nullptr, Qw,
                                              Kw, Vw, 8192, 3072, 1024, flag);
  attn_fwd<<<512, 256, 0, stream>>>(Qw, Kw, Vw, AOw);
  gemm_k<0><<<dim3(32, 8), 512, 0, stream>>>(AOw, WoutT, bout, d_out, nullptr,
                                             nullptr, nullptr, 8192, 1024, 1024,
                                             flag);
}